// Round 4
// baseline (83.501 us; speedup 1.0000x reference)
//
#include <hip/hip_runtime.h>

// GMLoss: bidirectional chamfer min + Geman-McClure penalty (MU=1).
// srcs, tgts: [B=8, D=3, N=4096] fp32. Output: scalar fp32.
//
// R4: LDS removed from the hot loop (R2/R3 both plateaued ~41us at ~50%
// issue efficiency regardless of occupancy/instr count -> LDS-path limited).
//  - Kernel A: transform both clouds into d_ws as float4(-2x,-2y,-2z,|t|^2),
//    16 groups x 4096 pts = 1 MB (L2-resident). Also zeros 16 partial cells.
//  - Kernel B: no LDS, no barriers in the main loop. Each wave holds 16
//    queries in regs; streams its group's 4096 float4 from global (L2) with
//    a 4-deep register prefetch ring (4 loads in flight, 256 VALU-cycles of
//    cover). 4 VALU/pair: 3 fma + 1 min; |q|^2 added after cross-lane min.
//    Block swizzle group=blk&15: each XCD's L2 serves ~2 groups (128 KB).
//  - Partial sums -> 16 cells (64B apart) in d_ws via atomicAdd (64/cell).
//  - Kernel C: sums cells, writes the exact scalar (no poison bias).

#define NPTS 4096
#define NB 8
#define QW 16

// ---------------- Kernel A: transform ----------------
__global__ __launch_bounds__(256)
void transform_kernel(const float* __restrict__ srcs,
                      const float* __restrict__ tgts,
                      float4* __restrict__ ws4) {
    const int gid = blockIdx.x * 256 + threadIdx.x;   // 0..65535
    const int dir = gid >> 15;          // 0: db = tgts, 1: db = srcs
    const int rem = gid & 32767;
    const int b   = rem >> 12;
    const int j   = rem & 4095;
    const float* dg = (dir == 0 ? tgts : srcs) + b * 3 * NPTS;
    const float x = dg[j], y = dg[NPTS + j], z = dg[2 * NPTS + j];
    ws4[gid] = make_float4(-2.0f * x, -2.0f * y, -2.0f * z,
                           fmaf(z, z, fmaf(y, y, x * x)));
    if (gid < 256) ((float*)(ws4 + 2 * NB * NPTS))[gid] = 0.0f;  // cells
}

// ---------------- Kernel B: chamfer main ----------------
#define COMP(T)                                                         \
    _Pragma("unroll")                                                   \
    for (int q = 0; q < QW; q++) {                                      \
        dmin[q] = fminf(dmin[q],                                        \
            fmaf(qx[q], (T).x, fmaf(qy[q], (T).y,                       \
            fmaf(qz[q], (T).z, (T).w))));                               \
    }

__global__ __launch_bounds__(256, 4)
void chamfer_gm_kernel(const float* __restrict__ srcs,
                       const float* __restrict__ tgts,
                       const float4* __restrict__ dbws,
                       float* __restrict__ cells) {
    __shared__ float sPart[4];

    const int blk   = blockIdx.x;        // 0..1023
    const int group = blk & 15;          // dir*8 + b  (XCD-friendly swizzle)
    const int chunk = blk >> 4;          // 0..63 query chunk
    const int dir   = group >> 3;
    const int b     = group & 7;

    const float* qg  = (dir == 0 ? srcs : tgts) + b * 3 * NPTS;
    const float4* db = dbws + group * NPTS;

    const int wave  = threadIdx.x >> 6;
    const int lane  = threadIdx.x & 63;
    const int qbase = chunk * 64 + wave * QW;

    float qx[QW], qy[QW], qz[QW], dmin[QW];
#pragma unroll
    for (int q = 0; q < QW; q++) {
        qx[q] = qg[qbase + q];
        qy[q] = qg[NPTS + qbase + q];
        qz[q] = qg[2 * NPTS + qbase + q];
        dmin[q] = 3.0e38f;
    }

    // 4-deep register prefetch ring over 64 chunks of 64 points
    float4 t0 = db[lane];
    float4 t1 = db[64 + lane];
    float4 t2 = db[128 + lane];
    float4 t3 = db[192 + lane];
    for (int it = 0; it < 60; it += 4) {
        const float4 n0 = db[(it + 4) * 64 + lane];
        const float4 n1 = db[(it + 5) * 64 + lane];
        const float4 n2 = db[(it + 6) * 64 + lane];
        const float4 n3 = db[(it + 7) * 64 + lane];
        COMP(t0); COMP(t1); COMP(t2); COMP(t3);
        t0 = n0; t1 = n1; t2 = n2; t3 = n3;
    }
    COMP(t0); COMP(t1); COMP(t2); COMP(t3);

    // cross-lane min, add |q|^2, GM penalty
    float acc = 0.0f;
#pragma unroll
    for (int q = 0; q < QW; q++) {
        float m = dmin[q];
#pragma unroll
        for (int off = 32; off > 0; off >>= 1)
            m = fminf(m, __shfl_xor(m, off, 64));
        const float qs = fmaf(qz[q], qz[q], fmaf(qy[q], qy[q], qx[q] * qx[q]));
        float d = fmaxf(m + qs, 0.0f);
        acc += d / (d + 1.0f);            // MU = 1
    }
    if (lane == 0) sPart[wave] = acc;
    __syncthreads();
    if (threadIdx.x == 0) {
        atomicAdd(&cells[group * 16],
                  sPart[0] + sPart[1] + sPart[2] + sPart[3]);
    }
}

// ---------------- Kernel C: finish ----------------
__global__ void finish_kernel(const float* __restrict__ cells,
                              float* __restrict__ out) {
    if (threadIdx.x == 0) {
        float s = 0.0f;
#pragma unroll
        for (int i = 0; i < 16; i++) s += cells[i * 16];
        out[0] = s * (1.0f / (NB * NPTS));
    }
}

extern "C" void kernel_launch(void* const* d_in, const int* in_sizes, int n_in,
                              void* d_out, int out_size, void* d_ws, size_t ws_size,
                              hipStream_t stream) {
    const float* srcs = (const float*)d_in[0];
    const float* tgts = (const float*)d_in[1];
    float* out  = (float*)d_out;
    float4* ws4 = (float4*)d_ws;
    float* cells = (float*)(ws4 + 2 * NB * NPTS);   // 1 KB after the 1 MB DB

    transform_kernel<<<dim3(256), dim3(256), 0, stream>>>(srcs, tgts, ws4);
    chamfer_gm_kernel<<<dim3(1024), dim3(256), 0, stream>>>(srcs, tgts, ws4, cells);
    finish_kernel<<<dim3(1), dim3(64), 0, stream>>>(cells, out);
}